// Round 1
// baseline (230.454 us; speedup 1.0000x reference)
//
#include <hip/hip_runtime.h>
#include <math.h>

#define B_ 32
#define Q_ 16
#define D_ 10
#define L_ 1000
#define E_ 300

// ---------------------------------------------------------------------------
// Kernel 1 (prep): per-batch query gather -> gate logits -> softmax,
// query norms, and score init with the affine constant C.
//   wq[b,q] = softmax(gate_logits)[b,q] * out_w * w2
//   nq[b,q] = ||emb[q_tok]||
//   score[b,d] = out_w*(w2*b1 + b2) + out_b      (atomics add onto this)
// ---------------------------------------------------------------------------
__global__ __launch_bounds__(256) void drmm_prep(
    const int* __restrict__ bq, const float* __restrict__ emb,
    const float* __restrict__ gate_w, const float* __restrict__ gate_b,
    const float* __restrict__ b1, const float* __restrict__ w2,
    const float* __restrict__ b2, const float* __restrict__ out_w,
    const float* __restrict__ out_b,
    float* __restrict__ wqBuf, float* __restrict__ nqBuf,
    float* __restrict__ score)
{
    const int b = blockIdx.x;
    const int tid = threadIdx.x;
    const int w = tid >> 6, lane = tid & 63;
    __shared__ float logits[Q_];

#pragma unroll
    for (int i = 0; i < 4; ++i) {
        const int q = w * 4 + i;                  // 4 waves x 4 -> q = 0..15
        const int tok = bq[b * Q_ + q];
        const float* row = emb + (size_t)tok * E_;
        // 300 floats = 75 float4 chunks: lanes 0..63 take chunk=lane,
        // lanes 0..10 also take chunk=64+lane.
        float4 dv = *(const float4*)(row + 4 * lane);
        float4 gv = *(const float4*)(gate_w + 4 * lane);
        float pd = dv.x * gv.x + dv.y * gv.y + dv.z * gv.z + dv.w * gv.w;
        float ps = dv.x * dv.x + dv.y * dv.y + dv.z * dv.z + dv.w * dv.w;
        if (lane < 11) {
            float4 dv2 = *(const float4*)(row + 256 + 4 * lane);
            float4 gv2 = *(const float4*)(gate_w + 256 + 4 * lane);
            pd += dv2.x * gv2.x + dv2.y * gv2.y + dv2.z * gv2.z + dv2.w * gv2.w;
            ps += dv2.x * dv2.x + dv2.y * dv2.y + dv2.z * dv2.z + dv2.w * dv2.w;
        }
#pragma unroll
        for (int off = 32; off > 0; off >>= 1) {
            pd += __shfl_xor(pd, off);
            ps += __shfl_xor(ps, off);
        }
        if (lane == 0) {
            logits[q] = pd + gate_b[0];
            nqBuf[b * Q_ + q] = sqrtf(ps);
        }
    }
    __syncthreads();

    if (tid == 0) {
        float m = -1e30f;
        for (int q = 0; q < Q_; ++q) m = fmaxf(m, logits[q]);
        float e[Q_];
        float s = 0.f;
        for (int q = 0; q < Q_; ++q) { e[q] = expf(logits[q] - m); s += e[q]; }
        const float sc = out_w[0] * w2[0] / s;
        for (int q = 0; q < Q_; ++q) wqBuf[b * Q_ + q] = e[q] * sc;
    }
    if (tid < D_)
        score[b * D_ + tid] = out_w[0] * (w2[0] * b1[0] + b2[0]) + out_b[0];
}

// ---------------------------------------------------------------------------
// Kernel 2 (main): one lane per doc term. Streams the doc embedding row in
// groups of 5 float4 chunks, double-buffered (10 loads in flight, prefetch
// issued one full compute-group ahead) to hide L2/L3 gather latency.
// Query rows are wave-uniform addresses (scalar-cache s_load_dwordx4).
// 16 dot accumulators + sumsq live in registers. Binning avoids division
// by comparing acc against k*denom. One atomic per block.
// Grid: 8-way L-split x D x B with 128-thread blocks -> 2560 blocks =
// exactly 10 blocks/CU (halves the tail imbalance of the 1280-block grid).
// ---------------------------------------------------------------------------

// Statically-indexed compute over one group of 5 chunks (rule #20: all
// buffer indices compile-time after unroll; kc only feeds address arith).
#define GROUP_COMPUTE(g0, buf)                                                 \
    _Pragma("unroll")                                                          \
    for (int i = 0; i < 5; ++i) {                                              \
        const int kc = (g0) * 5 + i;                                           \
        const float4 dv = buf[i];                                              \
        sq = fmaf(dv.x, dv.x,                                                  \
             fmaf(dv.y, dv.y, fmaf(dv.z, dv.z, fmaf(dv.w, dv.w, sq))));        \
        _Pragma("unroll")                                                      \
        for (int q = 0; q < Q_; ++q) {                                         \
            const float4 qv = *(const float4*)(qrow[q] + 4 * kc);              \
            acc[q] = fmaf(dv.w, qv.w,                                          \
                     fmaf(dv.z, qv.z,                                          \
                     fmaf(dv.y, qv.y, fmaf(dv.x, qv.x, acc[q]))));             \
        }                                                                      \
    }

__global__ __launch_bounds__(128) void drmm_main(
    const int* __restrict__ bq, const int* __restrict__ bdocs,
    const float* __restrict__ emb, const float* __restrict__ w1,
    const float* __restrict__ wqBuf, const float* __restrict__ nqBuf,
    float* __restrict__ score)
{
    const int ls = blockIdx.x;   // l-split 0..7 (125 terms each)
    const int d  = blockIdx.y;
    const int b  = blockIdx.z;
    const int tid = threadIdx.x;

    const float w10 = w1[0], w11 = w1[1], w12 = w1[2], w13 = w1[3], w14 = w1[4];

    // Per-block uniform query state: pointers/weights/norms stay in SGPRs.
    const float* qrow[Q_];
    float nqv[Q_], wqv[Q_];
#pragma unroll
    for (int q = 0; q < Q_; ++q) {
        qrow[q] = emb + (size_t)bq[b * Q_ + q] * E_;
        nqv[q]  = nqBuf[b * Q_ + q];
        wqv[q]  = wqBuf[b * Q_ + q];
    }

    float total = 0.f;
    if (tid < 125) {
        const int l = ls * 125 + tid;
        const int tok = bdocs[(b * D_ + d) * L_ + l];
        const float* drow = emb + (size_t)tok * E_;

        float acc[Q_];
#pragma unroll
        for (int q = 0; q < Q_; ++q) acc[q] = 0.f;
        float sq = 0.f;

        // Software-pipelined doc-row stream: 15 groups x 5 float4 chunks.
        float4 cur[5], nxt[5];
#pragma unroll
        for (int i = 0; i < 5; ++i)
            cur[i] = *(const float4*)(drow + 4 * i);

        for (int g = 0; g < 14; ++g) {
            const float* nb = drow + 20 * (g + 1);
#pragma unroll
            for (int i = 0; i < 5; ++i)
                nxt[i] = *(const float4*)(nb + 4 * i);

            GROUP_COMPUTE(g, cur)

#pragma unroll
            for (int i = 0; i < 5; ++i) cur[i] = nxt[i];
        }
        GROUP_COMPUTE(14, cur)

        const float nd = sqrtf(sq);
#pragma unroll
        for (int q = 0; q < Q_; ++q) {
            const float denom = fmaxf(nqv[q] * nd, 1e-8f);
            const float a = acc[q];
            // bins: [-1,-.5) [-.5,0) [0,.5) [.5,1) [1,1]; outside -> 0
            const float wv = (a < -denom)        ? 0.f
                           : (a < -0.5f * denom) ? w10
                           : (a < 0.f)           ? w11
                           : (a < 0.5f * denom)  ? w12
                           : (a < denom)         ? w13
                           : (a <= denom)        ? w14
                                                 : 0.f;
            total = fmaf(wqv[q], wv, total);
        }
    }

    // block reduce: wave butterfly -> LDS -> one atomic
#pragma unroll
    for (int off = 32; off > 0; off >>= 1) total += __shfl_xor(total, off);
    __shared__ float wsum[2];
    if ((tid & 63) == 0) wsum[tid >> 6] = total;
    __syncthreads();
    if (tid == 0)
        atomicAdd(&score[b * D_ + d], wsum[0] + wsum[1]);
}

extern "C" void kernel_launch(void* const* d_in, const int* in_sizes, int n_in,
                              void* d_out, int out_size, void* d_ws, size_t ws_size,
                              hipStream_t stream)
{
    const int*   bq     = (const int*)d_in[0];
    const int*   bdocs  = (const int*)d_in[1];
    const float* emb    = (const float*)d_in[2];
    const float* gate_w = (const float*)d_in[3];
    const float* gate_b = (const float*)d_in[4];
    const float* w1     = (const float*)d_in[5];
    const float* b1     = (const float*)d_in[6];
    const float* w2     = (const float*)d_in[7];
    const float* b2     = (const float*)d_in[8];
    const float* out_w  = (const float*)d_in[9];
    const float* out_b  = (const float*)d_in[10];

    float* score = (float*)d_out;
    float* wqBuf = (float*)d_ws;         // 512 floats
    float* nqBuf = wqBuf + B_ * Q_;      // 512 floats  (ws usage: 4 KiB)

    drmm_prep<<<dim3(B_), dim3(256), 0, stream>>>(
        bq, emb, gate_w, gate_b, b1, w2, b2, out_w, out_b, wqBuf, nqBuf, score);

    drmm_main<<<dim3(8, D_, B_), dim3(128), 0, stream>>>(
        bq, bdocs, emb, w1, wqBuf, nqBuf, score);
}